// Round 3
// baseline (840.579 us; speedup 1.0000x reference)
//
#include <hip/hip_runtime.h>
#include <cstdint>
#include <cstddef>

#define S_LEN   2048
#define D_MODEL 1536
#define NH      24
#define HDIM    64
#define WINDOW  512
#define NANCH   4

typedef __attribute__((ext_vector_type(8))) short short8;
typedef __attribute__((ext_vector_type(4))) float floatx4;

static __device__ __forceinline__ ushort f32_to_bf16(float f) {
    uint32_t u = __float_as_uint(f);
    uint32_t r = (u + 0x7FFFu + ((u >> 16) & 1u)) >> 16;
    return (ushort)r;
}

// ---------------- spike mask dtype sniff + normalize to int32 ----------------
__global__ __launch_bounds__(256) void spike_norm_kernel(
    const uint8_t* __restrict__ raw, int* __restrict__ norm) {
    __shared__ int sh[2];
    if (threadIdx.x == 0) { sh[0] = 0; sh[1] = 0; }
    __syncthreads();
    int f = 0, nz = 0;
    for (int i = threadIdx.x; i < S_LEN; i += 256) {
        uint8_t b = raw[i];
        if ((i & 3) == 3 && b == 0x3f) f++;          // 1.0f high byte
        if ((i & 3) != 0 && b != 0)    nz++;
    }
    if (f)  atomicAdd(&sh[0], f);
    if (nz) atomicAdd(&sh[1], nz);
    __syncthreads();
    const int mode = (sh[0] > 0) ? 2 : ((sh[1] > 0) ? 1 : 0);  // 2=f32 1=u8 0=i32
    for (int i = threadIdx.x; i < S_LEN; i += 256) {
        int v;
        if (mode == 2)      v = (((const float*)raw)[i] != 0.0f) ? 1 : 0;
        else if (mode == 1) v = raw[i] ? 1 : 0;
        else                v = (((const int*)raw)[i] != 0) ? 1 : 0;
        norm[i] = v;
    }
}

// ---------------- fp32 -> bf16 convert (vectorized x4) ----------------
__global__ void f2bf_kernel(const float* __restrict__ in, ushort* __restrict__ out, int n4) {
    int i = blockIdx.x * blockDim.x + threadIdx.x;
    if (i >= n4) return;
    float4 v = ((const float4*)in)[i];
    ushort4 o;
    o.x = f32_to_bf16(v.x);
    o.y = f32_to_bf16(v.y);
    o.z = f32_to_bf16(v.z);
    o.w = f32_to_bf16(v.w);
    ((ushort4*)out)[i] = o;
}

// ---------------- QKV projection: C[s,e] = sum_d x[s,d] * W[e,d] ----------------
__global__ __launch_bounds__(256) void gemm_qkv_kernel(
    const ushort* __restrict__ xb,   // [2048][1536] bf16
    const ushort* __restrict__ wb,   // [3][1536][1536] bf16
    float* __restrict__ qkv)         // [3][24][2048][64] fp32
{
    const int tm = blockIdx.x;   // 0..15  (S/128)
    const int tn = blockIdx.y;   // 0..11  (E/128)
    const int z  = blockIdx.z;   // 0..2
    const ushort* W = wb + (size_t)z * (D_MODEL * (size_t)D_MODEL);
    float* O = qkv + (size_t)z * (NH * S_LEN * HDIM);

    __shared__ __align__(16) ushort As[128 * 40];  // +8 pad per 32-elem row
    __shared__ __align__(16) ushort Bs[128 * 40];

    const int tid  = threadIdx.x;
    const int arow = tid >> 1;           // 0..127
    const int acol = (tid & 1) * 16;     // 0 or 16

    const ushort* gA = xb + (size_t)(tm * 128 + arow) * D_MODEL + acol;
    const ushort* gB = W  + (size_t)(tn * 128 + arow) * D_MODEL + acol;
    const int lA = arow * 40 + acol;

    const int wave = tid >> 6;
    const int lane = tid & 63;
    const int wm = (wave >> 1) * 64;
    const int wn = (wave & 1) * 64;
    const int lrow = lane & 15;
    const int lk   = (lane >> 4) * 8;

    int aoff[4], boff[4];
#pragma unroll
    for (int i = 0; i < 4; ++i) {
        aoff[i] = (wm + i * 16 + lrow) * 40 + lk;
        boff[i] = (wn + i * 16 + lrow) * 40 + lk;
    }

    floatx4 acc[4][4];
#pragma unroll
    for (int i = 0; i < 4; ++i)
#pragma unroll
        for (int j = 0; j < 4; ++j)
            acc[i][j] = (floatx4){0.f, 0.f, 0.f, 0.f};

    for (int kt = 0; kt < D_MODEL / 32; ++kt) {
        const uint4* pa = (const uint4*)(gA + kt * 32);
        const uint4* pb = (const uint4*)(gB + kt * 32);
        uint4 va0 = pa[0], va1 = pa[1];
        uint4 vb0 = pb[0], vb1 = pb[1];
        __syncthreads();
        *(uint4*)(&As[lA])     = va0;
        *(uint4*)(&As[lA + 8]) = va1;
        *(uint4*)(&Bs[lA])     = vb0;
        *(uint4*)(&Bs[lA + 8]) = vb1;
        __syncthreads();

        short8 af[4], bf[4];
#pragma unroll
        for (int i = 0; i < 4; ++i) af[i] = *(const short8*)(&As[aoff[i]]);
#pragma unroll
        for (int j = 0; j < 4; ++j) bf[j] = *(const short8*)(&Bs[boff[j]]);
#pragma unroll
        for (int i = 0; i < 4; ++i)
#pragma unroll
            for (int j = 0; j < 4; ++j)
                acc[i][j] = __builtin_amdgcn_mfma_f32_16x16x32_bf16(af[i], bf[j], acc[i][j], 0, 0, 0);
    }

    const int r0 = (lane >> 4) * 4;
    const int c0 = lane & 15;
#pragma unroll
    for (int i = 0; i < 4; ++i) {
#pragma unroll
        for (int j = 0; j < 4; ++j) {
            int col = tn * 128 + wn + j * 16 + c0;   // e
            int h = col >> 6, d = col & 63;
#pragma unroll
            for (int r = 0; r < 4; ++r) {
                int row = tm * 128 + wm + i * 16 + r0 + r;  // s
                O[((size_t)h * S_LEN + row) * HDIM + d] = acc[i][j][r];
            }
        }
    }
}

// ---------------- RoPE (in place on Q and K, fp32) ----------------
__global__ void rope_kernel(float* __restrict__ Q, float* __restrict__ K) {
    int p = blockIdx.x * blockDim.x + threadIdx.x;   // < NH*S_LEN*32
    float* base = (blockIdx.y == 0) ? Q : K;
    int i   = p & 31;          // freq index
    int row = p >> 5;          // h*S + s
    int s   = row & (S_LEN - 1);
    float inv_freq = expf(-(float)i * (0.2878231366242557f)); // ln(10000)/32
    float ang = (float)s * inv_freq;
    float c, sn;
    sincosf(ang, &sn, &c);   // FIXED: sincosf(x, sin*, cos*) — sine pointer FIRST
    float x0 = base[row * 64 + i];
    float x1 = base[row * 64 + i + 32];
    base[row * 64 + i]      = x0 * c - x1 * sn;
    base[row * 64 + i + 32] = x1 * c + x0 * sn;
}

// ---------------- attention: one block per (q, h) ----------------
__global__ __launch_bounds__(256) void attn_kernel(
    const float* __restrict__ Q,   // [H][S][64]
    const float* __restrict__ K,
    const float* __restrict__ V,
    const int*   __restrict__ spike,  // [S] normalized 0/1
    float* __restrict__ out)          // [S][1536]
{
    const int q   = blockIdx.x;
    const int h   = blockIdx.y;
    const int tid = threadIdx.x;
    const int out_base = q * D_MODEL + h * HDIM;

    __shared__ float qrow[64];
    __shared__ float sc[520];
    __shared__ float red[256];

    if (spike[q] == 0) {
        if (tid < 64) out[out_base + tid] = 0.f;
        return;
    }

    const int wstart = (q > WINDOW) ? (q - WINDOW) : 0;
    const int na = (wstart < NANCH) ? wstart : NANCH;   // anchors strictly below window
    const int nk = na + (q - wstart + 1);

    if (tid < 64) qrow[tid] = Q[((size_t)h * S_LEN + q) * HDIM + tid];
    __syncthreads();

    for (int t = tid; t < nk; t += 256) {
        int k = (t < na) ? t : (wstart + (t - na));
        float s;
        if (spike[k] != 0) {
            const float* kr = K + ((size_t)h * S_LEN + k) * HDIM;
            float acc = 0.f;
#pragma unroll
            for (int d = 0; d < 64; ++d) acc += qrow[d] * kr[d];
            s = acc * 0.125f;
        } else {
            s = -INFINITY;
        }
        sc[t] = s;
    }
    __syncthreads();

    float m = -INFINITY;
    for (int t = tid; t < nk; t += 256) m = fmaxf(m, sc[t]);
    red[tid] = m;
    __syncthreads();
    for (int off = 128; off > 0; off >>= 1) {
        if (tid < off) red[tid] = fmaxf(red[tid], red[tid + off]);
        __syncthreads();
    }
    m = red[0];
    __syncthreads();

    if (m == -INFINITY) {
        if (tid < 64) out[out_base + tid] = 0.f;
        return;
    }

    float psum = 0.f;
    for (int t = tid; t < nk; t += 256) {
        float w = __expf(sc[t] - m);
        sc[t] = w;
        psum += w;
    }
    red[tid] = psum;
    __syncthreads();
    for (int off = 128; off > 0; off >>= 1) {
        if (tid < off) red[tid] += red[tid + off];
        __syncthreads();
    }
    float inv = 1.0f / red[0];
    __syncthreads();

    const int d = tid & 63;
    const int part = tid >> 6;
    float acc = 0.f;
    for (int t = part; t < nk; t += 4) {
        int k = (t < na) ? t : (wstart + (t - na));
        acc += sc[t] * V[((size_t)h * S_LEN + k) * HDIM + d];
    }
    red[part * 64 + d] = acc;
    __syncthreads();
    if (tid < 64) {
        float r = red[tid] + red[64 + tid] + red[128 + tid] + red[192 + tid];
        out[out_base + tid] = r * inv;
    }
}

extern "C" void kernel_launch(void* const* d_in, const int* in_sizes, int n_in,
                              void* d_out, int out_size, void* d_ws, size_t ws_size,
                              hipStream_t stream) {
    const float* x     = (const float*)d_in[0];
    const uint8_t* spike_raw = (const uint8_t*)d_in[1];
    const float* Wq    = (const float*)d_in[2];
    const float* Wk    = (const float*)d_in[3];
    const float* Wv    = (const float*)d_in[4];
    float* out = (float*)d_out;

    const size_t xb_elems  = (size_t)S_LEN * D_MODEL;          // 3,145,728
    const size_t w_elems   = (size_t)D_MODEL * D_MODEL;        // 2,359,296
    const size_t qkv_elems = (size_t)NH * S_LEN * HDIM;        // 3,145,728 per tensor

    char* ws = (char*)d_ws;
    ushort* xb = (ushort*)ws;                                       // 6,291,456 B
    ushort* wb = (ushort*)(ws + xb_elems * 2);                      // 14,155,776 B
    float* qkv = (float*)(ws + xb_elems * 2 + 3 * w_elems * 2);     // 37,748,736 B
    int* spike_i = (int*)(ws + xb_elems * 2 + 3 * w_elems * 2 + 3 * qkv_elems * 4);
    float* Qm = qkv;
    float* Km = qkv + qkv_elems;
    float* Vm = qkv + 2 * qkv_elems;

    const size_t need = xb_elems * 2 + 3 * w_elems * 2 + 3 * qkv_elems * 4 + S_LEN * 4;
    if (ws_size < need) return;

    // 0) normalize spike mask dtype
    spike_norm_kernel<<<1, 256, 0, stream>>>(spike_raw, spike_i);

    // 1) fp32 -> bf16
    {
        int n4 = (int)(xb_elems / 4);
        f2bf_kernel<<<(n4 + 255) / 256, 256, 0, stream>>>(x, xb, n4);
        int w4 = (int)(w_elems / 4);
        f2bf_kernel<<<(w4 + 255) / 256, 256, 0, stream>>>(Wq, wb, w4);
        f2bf_kernel<<<(w4 + 255) / 256, 256, 0, stream>>>(Wk, wb + w_elems, w4);
        f2bf_kernel<<<(w4 + 255) / 256, 256, 0, stream>>>(Wv, wb + 2 * w_elems, w4);
    }

    // 2) QKV projections (bf16 MFMA)
    gemm_qkv_kernel<<<dim3(S_LEN / 128, D_MODEL / 128, 3), 256, 0, stream>>>(xb, wb, qkv);

    // 3) RoPE on Q and K
    {
        int pairs = NH * S_LEN * 32;
        rope_kernel<<<dim3(pairs / 256, 2), 256, 0, stream>>>(Qm, Km);
    }

    // 4) attention
    attn_kernel<<<dim3(S_LEN, NH), 256, 0, stream>>>(Qm, Km, Vm, spike_i, out);
}

// Round 4
// 252.959 us; speedup vs baseline: 3.3230x; 3.3230x over previous
//
#include <hip/hip_runtime.h>
#include <cstdint>
#include <cstddef>

#define S_LEN   2048
#define D_MODEL 1536
#define NH      24
#define HDIM    64
#define WINDOW  512
#define NANCH   4

typedef __attribute__((ext_vector_type(8))) short short8;
typedef __attribute__((ext_vector_type(4))) float floatx4;

static __device__ __forceinline__ ushort f32_to_bf16(float f) {
    uint32_t u = __float_as_uint(f);
    uint32_t r = (u + 0x7FFFu + ((u >> 16) & 1u)) >> 16;
    return (ushort)r;
}

// ---------------- spike mask dtype sniff + normalize to int32 ----------------
__global__ __launch_bounds__(256) void spike_norm_kernel(
    const uint8_t* __restrict__ raw, int* __restrict__ norm) {
    __shared__ int sh[2];
    if (threadIdx.x == 0) { sh[0] = 0; sh[1] = 0; }
    __syncthreads();
    int f = 0, nz = 0;
    for (int i = threadIdx.x; i < S_LEN; i += 256) {
        uint8_t b = raw[i];
        if ((i & 3) == 3 && b == 0x3f) f++;          // 1.0f high byte
        if ((i & 3) != 0 && b != 0)    nz++;
    }
    if (f)  atomicAdd(&sh[0], f);
    if (nz) atomicAdd(&sh[1], nz);
    __syncthreads();
    const int mode = (sh[0] > 0) ? 2 : ((sh[1] > 0) ? 1 : 0);  // 2=f32 1=u8 0=i32
    for (int i = threadIdx.x; i < S_LEN; i += 256) {
        int v;
        if (mode == 2)      v = (((const float*)raw)[i] != 0.0f) ? 1 : 0;
        else if (mode == 1) v = raw[i] ? 1 : 0;
        else                v = (((const int*)raw)[i] != 0) ? 1 : 0;
        norm[i] = v;
    }
}

// ---------------- fp32 -> bf16 convert (vectorized x4) ----------------
__global__ void f2bf_kernel(const float* __restrict__ in, ushort* __restrict__ out, int n4) {
    int i = blockIdx.x * blockDim.x + threadIdx.x;
    if (i >= n4) return;
    float4 v = ((const float4*)in)[i];
    ushort4 o;
    o.x = f32_to_bf16(v.x);
    o.y = f32_to_bf16(v.y);
    o.z = f32_to_bf16(v.z);
    o.w = f32_to_bf16(v.w);
    ((ushort4*)out)[i] = o;
}

// ---------------- QKV projection: C[s,e] = sum_d x[s,d] * W[e,d] ----------------
// z=0 -> Qm fp32 [H][S][64]; z=1 -> Km fp32 [H][S][64]; z=2 -> Vt bf16 [H][64][S]
__global__ __launch_bounds__(256) void gemm_qkv_kernel(
    const ushort* __restrict__ xb,   // [2048][1536] bf16
    const ushort* __restrict__ wb,   // [3][1536][1536] bf16
    float* __restrict__ Qm, float* __restrict__ Km,
    ushort* __restrict__ Vt)
{
    const int tm = blockIdx.x;   // 0..15  (S/128)
    const int tn = blockIdx.y;   // 0..11  (E/128)
    const int z  = blockIdx.z;   // 0..2
    const ushort* W = wb + (size_t)z * (D_MODEL * (size_t)D_MODEL);

    __shared__ __align__(16) ushort As[128 * 40];  // +8 pad per 32-elem row
    __shared__ __align__(16) ushort Bs[128 * 40];

    const int tid  = threadIdx.x;
    const int arow = tid >> 1;           // 0..127
    const int acol = (tid & 1) * 16;     // 0 or 16

    const ushort* gA = xb + (size_t)(tm * 128 + arow) * D_MODEL + acol;
    const ushort* gB = W  + (size_t)(tn * 128 + arow) * D_MODEL + acol;
    const int lA = arow * 40 + acol;

    const int wave = tid >> 6;
    const int lane = tid & 63;
    const int wm = (wave >> 1) * 64;
    const int wn = (wave & 1) * 64;
    const int lrow = lane & 15;
    const int lk   = (lane >> 4) * 8;

    int aoff[4], boff[4];
#pragma unroll
    for (int i = 0; i < 4; ++i) {
        aoff[i] = (wm + i * 16 + lrow) * 40 + lk;
        boff[i] = (wn + i * 16 + lrow) * 40 + lk;
    }

    floatx4 acc[4][4];
#pragma unroll
    for (int i = 0; i < 4; ++i)
#pragma unroll
        for (int j = 0; j < 4; ++j)
            acc[i][j] = (floatx4){0.f, 0.f, 0.f, 0.f};

    for (int kt = 0; kt < D_MODEL / 32; ++kt) {
        const uint4* pa = (const uint4*)(gA + kt * 32);
        const uint4* pb = (const uint4*)(gB + kt * 32);
        uint4 va0 = pa[0], va1 = pa[1];
        uint4 vb0 = pb[0], vb1 = pb[1];
        __syncthreads();
        *(uint4*)(&As[lA])     = va0;
        *(uint4*)(&As[lA + 8]) = va1;
        *(uint4*)(&Bs[lA])     = vb0;
        *(uint4*)(&Bs[lA + 8]) = vb1;
        __syncthreads();

        short8 af[4], bf[4];
#pragma unroll
        for (int i = 0; i < 4; ++i) af[i] = *(const short8*)(&As[aoff[i]]);
#pragma unroll
        for (int j = 0; j < 4; ++j) bf[j] = *(const short8*)(&Bs[boff[j]]);
#pragma unroll
        for (int i = 0; i < 4; ++i)
#pragma unroll
            for (int j = 0; j < 4; ++j)
                acc[i][j] = __builtin_amdgcn_mfma_f32_16x16x32_bf16(af[i], bf[j], acc[i][j], 0, 0, 0);
    }

    const int r0 = (lane >> 4) * 4;
    const int c0 = lane & 15;
    if (z < 2) {
        float* O = (z == 0) ? Qm : Km;
#pragma unroll
        for (int i = 0; i < 4; ++i) {
#pragma unroll
            for (int j = 0; j < 4; ++j) {
                int col = tn * 128 + wn + j * 16 + c0;   // e
                int h = col >> 6, d = col & 63;
#pragma unroll
                for (int r = 0; r < 4; ++r) {
                    int row = tm * 128 + wm + i * 16 + r0 + r;  // s
                    O[((size_t)h * S_LEN + row) * HDIM + d] = acc[i][j][r];
                }
            }
        }
    } else {
        // V transposed bf16: Vt[h][d][s]
#pragma unroll
        for (int i = 0; i < 4; ++i) {
#pragma unroll
            for (int j = 0; j < 4; ++j) {
                int col = tn * 128 + wn + j * 16 + c0;   // e
                int h = col >> 6, d = col & 63;
                int row0 = tm * 128 + wm + i * 16 + r0;  // s, 4 contiguous
                ushort4 o;
                o.x = f32_to_bf16(acc[i][j][0]);
                o.y = f32_to_bf16(acc[i][j][1]);
                o.z = f32_to_bf16(acc[i][j][2]);
                o.w = f32_to_bf16(acc[i][j][3]);
                *(ushort4*)&Vt[((size_t)h * HDIM + d) * S_LEN + row0] = o;
            }
        }
    }
}

// ---------------- RoPE fp32 -> bf16 (Q and K) ----------------
__global__ void rope_bf16_kernel(const float* __restrict__ Qm, const float* __restrict__ Km,
                                 ushort* __restrict__ Qb, ushort* __restrict__ Kb) {
    int p = blockIdx.x * blockDim.x + threadIdx.x;   // < NH*S_LEN*32
    const float* src = blockIdx.y ? Km : Qm;
    ushort* dst = blockIdx.y ? Kb : Qb;
    int i   = p & 31;          // freq index
    int row = p >> 5;          // h*S + s
    int s   = row & (S_LEN - 1);
    float inv_freq = expf(-(float)i * (0.2878231366242557f)); // ln(10000)/32
    float ang = (float)s * inv_freq;
    float c, sn;
    sincosf(ang, &sn, &c);     // sincosf(x, sin*, cos*)
    float x0 = src[row * 64 + i];
    float x1 = src[row * 64 + i + 32];
    dst[row * 64 + i]      = f32_to_bf16(x0 * c - x1 * sn);
    dst[row * 64 + i + 32] = f32_to_bf16(x1 * c + x0 * sn);
}

// ---------------- flash attention: MFMA, one block per (q-tile=64, head) ----------------
__global__ __launch_bounds__(256) void flash_attn_kernel(
    const ushort* __restrict__ Qb,   // [H][S][64] bf16 roped
    const ushort* __restrict__ Kb,   // [H][S][64] bf16 roped
    const ushort* __restrict__ Vt,   // [H][64][S] bf16
    const int*   __restrict__ spike, // [S] 0/1
    float* __restrict__ out)         // [S][1536]
{
    const int qt = blockIdx.x;       // 0..31
    const int h  = blockIdx.y;       // 0..23
    const int qs = qt * 64;
    const int tid  = threadIdx.x;
    const int wave = tid >> 6;
    const int lane = tid & 63;
    const int quad = lane >> 4;
    const int l16  = lane & 15;

    __shared__ __align__(16) ushort Pst[4][16 * 72];   // per-wave P staging (stride 72)

    // Q A-fragments: rows qs + wave*16 + l16; k-dim = kk*32 + quad*8 + j
    const ushort* Qp = Qb + ((size_t)h * S_LEN + qs + wave * 16 + l16) * HDIM;
    const short8 qf0 = *(const short8*)(Qp + quad * 8);
    const short8 qf1 = *(const short8*)(Qp + 32 + quad * 8);

    // C-layout row ownership: qs + wave*16 + quad*4 + r
    const int qrow0 = qs + wave * 16 + quad * 4;

    float m_i[4], l_i[4];
    floatx4 Oacc[4];
#pragma unroll
    for (int r = 0; r < 4; ++r) { m_i[r] = -INFINITY; l_i[r] = 0.f; }
#pragma unroll
    for (int j = 0; j < 4; ++j) Oacc[j] = (floatx4){0.f, 0.f, 0.f, 0.f};

    const int lo = (qs > WINDOW ? qs - WINDOW : 0) >> 6;

    for (int t = (lo > 0 ? -1 : 0); t <= qt; t = (t == -1 ? lo : t + 1)) {
        const int kt = (t == -1) ? 0 : t;
        const int kbase = kt * 64;

        // ---- QK^T ----
        floatx4 Sacc[4];
#pragma unroll
        for (int j = 0; j < 4; ++j) {
            const ushort* Kp = Kb + ((size_t)h * S_LEN + kbase + j * 16 + l16) * HDIM;
            short8 kf0 = *(const short8*)(Kp + quad * 8);
            short8 kf1 = *(const short8*)(Kp + 32 + quad * 8);
            floatx4 s = (floatx4){0.f, 0.f, 0.f, 0.f};
            s = __builtin_amdgcn_mfma_f32_16x16x32_bf16(qf0, kf0, s, 0, 0, 0);
            s = __builtin_amdgcn_mfma_f32_16x16x32_bf16(qf1, kf1, s, 0, 0, 0);
            Sacc[j] = s;
        }

        int spk[4];
#pragma unroll
        for (int j = 0; j < 4; ++j) spk[j] = spike[kbase + j * 16 + l16];

        // ---- mask + online softmax ----
        float p[4][4];   // [j][r]
#pragma unroll
        for (int r = 0; r < 4; ++r) {
            const int q = qrow0 + r;
            float mx = -INFINITY;
#pragma unroll
            for (int j = 0; j < 4; ++j) {
                const int k = kbase + j * 16 + l16;
                const bool valid = (k <= q) && (((q - k) <= WINDOW) || (k < NANCH)) && (spk[j] != 0);
                float s = valid ? Sacc[j][r] * 0.125f : -INFINITY;
                p[j][r] = s;
                mx = fmaxf(mx, s);
            }
            mx = fmaxf(mx, __shfl_xor(mx, 1));
            mx = fmaxf(mx, __shfl_xor(mx, 2));
            mx = fmaxf(mx, __shfl_xor(mx, 4));
            mx = fmaxf(mx, __shfl_xor(mx, 8));
            const float mnew = fmaxf(m_i[r], mx);
            const float alpha = (m_i[r] == -INFINITY) ? 0.f : __expf(m_i[r] - mnew);
            float rs = 0.f;
#pragma unroll
            for (int j = 0; j < 4; ++j) {
                float w = (p[j][r] == -INFINITY) ? 0.f : __expf(p[j][r] - mnew);
                p[j][r] = w;
                rs += w;
            }
            rs += __shfl_xor(rs, 1);
            rs += __shfl_xor(rs, 2);
            rs += __shfl_xor(rs, 4);
            rs += __shfl_xor(rs, 8);
            l_i[r] = l_i[r] * alpha + rs;
            m_i[r] = mnew;
#pragma unroll
            for (int j = 0; j < 4; ++j) Oacc[j][r] *= alpha;
        }

        // ---- P -> LDS (bf16, C-layout -> A-layout transpose) ----
        ushort* myP = Pst[wave];
#pragma unroll
        for (int r = 0; r < 4; ++r)
#pragma unroll
            for (int j = 0; j < 4; ++j)
                myP[(quad * 4 + r) * 72 + j * 16 + l16] = f32_to_bf16(p[j][r]);
        __syncthreads();

        // ---- P @ V ----
#pragma unroll
        for (int kk = 0; kk < 2; ++kk) {
            const short8 pf = *(const short8*)(myP + l16 * 72 + kk * 32 + quad * 8);
#pragma unroll
            for (int j = 0; j < 4; ++j) {
                const ushort* Vp = Vt + ((size_t)h * HDIM + j * 16 + l16) * S_LEN
                                 + kbase + kk * 32 + quad * 8;
                short8 vf = *(const short8*)Vp;
                Oacc[j] = __builtin_amdgcn_mfma_f32_16x16x32_bf16(pf, vf, Oacc[j], 0, 0, 0);
            }
        }
        __syncthreads();
    }

    // ---- epilogue: normalize, apply spike[q], write ----
#pragma unroll
    for (int r = 0; r < 4; ++r) {
        const int q = qrow0 + r;
        const float inv = (l_i[r] > 0.f && spike[q] != 0) ? (1.0f / l_i[r]) : 0.f;
#pragma unroll
        for (int j = 0; j < 4; ++j)
            out[(size_t)q * D_MODEL + h * HDIM + j * 16 + l16] = Oacc[j][r] * inv;
    }
}

extern "C" void kernel_launch(void* const* d_in, const int* in_sizes, int n_in,
                              void* d_out, int out_size, void* d_ws, size_t ws_size,
                              hipStream_t stream) {
    const float* x     = (const float*)d_in[0];
    const uint8_t* spike_raw = (const uint8_t*)d_in[1];
    const float* Wq    = (const float*)d_in[2];
    const float* Wk    = (const float*)d_in[3];
    const float* Wv    = (const float*)d_in[4];
    float* out = (float*)d_out;

    const size_t xb_elems  = (size_t)S_LEN * D_MODEL;          // 3,145,728
    const size_t w_elems   = (size_t)D_MODEL * D_MODEL;        // 2,359,296
    const size_t hs_elems  = (size_t)NH * S_LEN * HDIM;        // 3,145,728

    // Workspace layout (region A reused: xb+wb during GEMM, Qb+Kb after)
    char* ws = (char*)d_ws;
    const size_t offA  = 0;                                    // xb (6.29MB) + wb (14.16MB)
    const size_t offQm = offA + xb_elems * 2 + 3 * w_elems * 2;   // 20,447,232
    const size_t offKm = offQm + hs_elems * 4;                    // +12.58MB
    const size_t offVt = offKm + hs_elems * 4;                    // +12.58MB
    const size_t offSp = offVt + hs_elems * 2;                    // +6.29MB
    const size_t need  = offSp + S_LEN * 4;

    ushort* xb = (ushort*)(ws + offA);
    ushort* wb = (ushort*)(ws + offA + xb_elems * 2);
    ushort* Qb = (ushort*)(ws + offA);                  // reuses xb (after GEMM)
    ushort* Kb = (ushort*)(ws + offA + hs_elems * 2);   // reuses wb head (after GEMM)
    float*  Qm = (float*)(ws + offQm);
    float*  Km = (float*)(ws + offKm);
    ushort* Vt = (ushort*)(ws + offVt);
    int* spike_i = (int*)(ws + offSp);

    if (ws_size < need) return;

    // 0) normalize spike mask dtype
    spike_norm_kernel<<<1, 256, 0, stream>>>(spike_raw, spike_i);

    // 1) fp32 -> bf16 inputs
    {
        int n4 = (int)(xb_elems / 4);
        f2bf_kernel<<<(n4 + 255) / 256, 256, 0, stream>>>(x, xb, n4);
        int w4 = (int)(w_elems / 4);
        f2bf_kernel<<<(w4 + 255) / 256, 256, 0, stream>>>(Wq, wb, w4);
        f2bf_kernel<<<(w4 + 255) / 256, 256, 0, stream>>>(Wk, wb + w_elems, w4);
        f2bf_kernel<<<(w4 + 255) / 256, 256, 0, stream>>>(Wv, wb + 2 * w_elems, w4);
    }

    // 2) QKV projections (bf16 MFMA); V written transposed bf16
    gemm_qkv_kernel<<<dim3(S_LEN / 128, D_MODEL / 128, 3), 256, 0, stream>>>(xb, wb, Qm, Km, Vt);

    // 3) RoPE + bf16 convert for Q, K (overwrites xb/wb region — GEMM is done)
    {
        int pairs = NH * S_LEN * 32;
        rope_bf16_kernel<<<dim3(pairs / 256, 2), 256, 0, stream>>>(Qm, Km, Qb, Kb);
    }

    // 4) flash attention (MFMA)
    flash_attn_kernel<<<dim3(S_LEN / 64, NH), 256, 0, stream>>>(Qb, Kb, Vt, spike_i, out);
}

// Round 5
// 234.332 us; speedup vs baseline: 3.5871x; 1.0795x over previous
//
#include <hip/hip_runtime.h>
#include <cstdint>
#include <cstddef>

#define S_LEN   2048
#define D_MODEL 1536
#define NH      24
#define HDIM    64
#define WINDOW  512
#define NANCH   4

typedef __attribute__((ext_vector_type(8))) short short8;
typedef __attribute__((ext_vector_type(4))) float floatx4;

#define ASYNC_COPY16(g, l) \
    __builtin_amdgcn_global_load_lds((const __attribute__((address_space(1))) uint32_t*)(g), \
                                     (__attribute__((address_space(3))) uint32_t*)(l), 16, 0, 0)

static __device__ __forceinline__ ushort f32_to_bf16(float f) {
    uint32_t u = __float_as_uint(f);
    uint32_t r = (u + 0x7FFFu + ((u >> 16) & 1u)) >> 16;
    return (ushort)r;
}

// ---------------- prep: RoPE cos/sin table + spike mask normalize ----------------
// blocks 0..255: cs[s][0..31]=cos(s*invf_i), cs[s][32..63]=sin(s*invf_i)
// block 256: spike dtype sniff + normalize to int32
__global__ __launch_bounds__(256) void prep_kernel(
    const uint8_t* __restrict__ raw, int* __restrict__ norm, float* __restrict__ cs) {
    if (blockIdx.x < 256) {
        int idx = blockIdx.x * 256 + threadIdx.x;   // 65536 = s*32 + i
        int s = idx >> 5, i = idx & 31;
        float inv_freq = expf(-(float)i * 0.2878231366242557f); // ln(10000)/32
        float c, sn;
        sincosf((float)s * inv_freq, &sn, &c);
        cs[s * 64 + i]      = c;
        cs[s * 64 + 32 + i] = sn;
        return;
    }
    __shared__ int sh[2];
    if (threadIdx.x == 0) { sh[0] = 0; sh[1] = 0; }
    __syncthreads();
    int f = 0, nz = 0;
    for (int i = threadIdx.x; i < S_LEN; i += 256) {
        uint8_t b = raw[i];
        if ((i & 3) == 3 && b == 0x3f) f++;          // 1.0f high byte
        if ((i & 3) != 0 && b != 0)    nz++;
    }
    if (f)  atomicAdd(&sh[0], f);
    if (nz) atomicAdd(&sh[1], nz);
    __syncthreads();
    const int mode = (sh[0] > 0) ? 2 : ((sh[1] > 0) ? 1 : 0);  // 2=f32 1=u8 0=i32
    for (int i = threadIdx.x; i < S_LEN; i += 256) {
        int v;
        if (mode == 2)      v = (((const float*)raw)[i] != 0.0f) ? 1 : 0;
        else if (mode == 1) v = raw[i] ? 1 : 0;
        else                v = (((const int*)raw)[i] != 0) ? 1 : 0;
        norm[i] = v;
    }
}

// ---------------- fp32 -> bf16 convert: x + Wq + Wk + Wv in one launch ----------------
__global__ void f2bf4_kernel(const float* __restrict__ x,
                             const float* __restrict__ wq, const float* __restrict__ wk,
                             const float* __restrict__ wv,
                             ushort* __restrict__ xb, ushort* __restrict__ wb,
                             int xq4, int wq4) {
    const int which = blockIdx.y;
    const size_t w_elems = (size_t)D_MODEL * D_MODEL;
    const float* src; ushort* dst; int n4;
    if (which == 0)      { src = x;  dst = xb;               n4 = xq4; }
    else if (which == 1) { src = wq; dst = wb;               n4 = wq4; }
    else if (which == 2) { src = wk; dst = wb + w_elems;     n4 = wq4; }
    else                 { src = wv; dst = wb + 2 * w_elems; n4 = wq4; }
    int i = blockIdx.x * blockDim.x + threadIdx.x;
    if (i >= n4) return;
    float4 v = ((const float4*)src)[i];
    ushort4 o;
    o.x = f32_to_bf16(v.x);
    o.y = f32_to_bf16(v.y);
    o.z = f32_to_bf16(v.z);
    o.w = f32_to_bf16(v.w);
    ((ushort4*)dst)[i] = o;
}

// ---------------- QKV projection + fused RoPE ----------------
// C[s,e] = sum_d x[s,d] * W[e,d]
// z=0 -> Qb bf16 [H][S][64] (roped); z=1 -> Kb bf16 (roped); z=2 -> Vt bf16 [H][64][S]
// Staging via global_load_lds width=16 (m97 pattern): unpadded 64B rows.
__global__ __launch_bounds__(256) void gemm_qkv_kernel(
    const ushort* __restrict__ xb,   // [2048][1536] bf16
    const ushort* __restrict__ wb,   // [3][1536][1536] bf16
    const float*  __restrict__ cs,   // [2048][64] cos|sin table
    ushort* __restrict__ Qb, ushort* __restrict__ Kb, ushort* __restrict__ Vt)
{
    const int tm = blockIdx.x;   // 0..15  (S/128)
    const int tn = blockIdx.y;   // 0..11  (E/128)
    const int z  = blockIdx.z;   // 0..2
    const ushort* W = wb + (size_t)z * (D_MODEL * (size_t)D_MODEL);

    __shared__ __align__(16) ushort As[128 * 32];  // 8 KB, row-major, 64B rows
    __shared__ __align__(16) ushort Bs[128 * 32];

    const int tid  = threadIdx.x;
    const int wave = tid >> 6;
    const int lane = tid & 63;

    // staging: wave w covers rows [w*32, w*32+32) via 2 insts of 16 rows (1024 B each)
    // lane l: row-in-16 = l>>2, 16B chunk = l&3
    const int srow = wave * 32 + (lane >> 2);
    const int scol = (lane & 3) * 8;               // ushorts
    const ushort* gA0 = xb + (size_t)(tm * 128 + srow) * D_MODEL + scol;
    const ushort* gA1 = gA0 + (size_t)16 * D_MODEL;
    const ushort* gB0 = W  + (size_t)(tn * 128 + srow) * D_MODEL + scol;
    const ushort* gB1 = gB0 + (size_t)16 * D_MODEL;
    ushort* lA0 = &As[wave * 1024];       // 32 rows * 32 cols
    ushort* lA1 = &As[wave * 1024 + 512];
    ushort* lB0 = &Bs[wave * 1024];
    ushort* lB1 = &Bs[wave * 1024 + 512];

    const int wm = (wave >> 1) * 64;
    const int wn = (wave & 1) * 64;
    const int lrow  = lane & 15;
    const int quadk = (lane >> 4) * 8;    // k-chunk (ushorts)

    floatx4 acc[4][4];
#pragma unroll
    for (int i = 0; i < 4; ++i)
#pragma unroll
        for (int j = 0; j < 4; ++j)
            acc[i][j] = (floatx4){0.f, 0.f, 0.f, 0.f};

    for (int kt = 0; kt < D_MODEL / 32; ++kt) {
        __syncthreads();                  // prev iter's LDS reads complete
        ASYNC_COPY16(gA0 + kt * 32, lA0);
        ASYNC_COPY16(gA1 + kt * 32, lA1);
        ASYNC_COPY16(gB0 + kt * 32, lB0);
        ASYNC_COPY16(gB1 + kt * 32, lB1);
        __syncthreads();                  // drains vmcnt -> LDS visible

        short8 af[4], bf[4];
#pragma unroll
        for (int i = 0; i < 4; ++i) af[i] = *(const short8*)(&As[(wm + i * 16 + lrow) * 32 + quadk]);
#pragma unroll
        for (int j = 0; j < 4; ++j) bf[j] = *(const short8*)(&Bs[(wn + j * 16 + lrow) * 32 + quadk]);
#pragma unroll
        for (int i = 0; i < 4; ++i)
#pragma unroll
            for (int j = 0; j < 4; ++j)
                acc[i][j] = __builtin_amdgcn_mfma_f32_16x16x32_bf16(af[i], bf[j], acc[i][j], 0, 0, 0);
    }

    const int r0 = (lane >> 4) * 4;
    const int c0 = lane & 15;
    if (z < 2) {
        // fused RoPE: cols (j, j+2) are the (d, d+32) rotation pair, same head
        ushort* O = (z == 0) ? Qb : Kb;
#pragma unroll
        for (int i = 0; i < 4; ++i) {
#pragma unroll
            for (int j = 0; j < 2; ++j) {
                const int col = tn * 128 + wn + j * 16 + c0;
                const int h = col >> 6, d0 = col & 63;     // d0 in [0,32)
#pragma unroll
                for (int r = 0; r < 4; ++r) {
                    const int row = tm * 128 + wm + i * 16 + r0 + r;  // s
                    const float c  = cs[row * 64 + d0];
                    const float sn = cs[row * 64 + 32 + d0];
                    const float x0 = acc[i][j][r];
                    const float x1 = acc[i][j + 2][r];
                    const size_t base = ((size_t)h * S_LEN + row) * HDIM;
                    O[base + d0]      = f32_to_bf16(x0 * c - x1 * sn);
                    O[base + d0 + 32] = f32_to_bf16(x1 * c + x0 * sn);
                }
            }
        }
    } else {
        // V transposed bf16: Vt[h][d][s]
#pragma unroll
        for (int i = 0; i < 4; ++i) {
#pragma unroll
            for (int j = 0; j < 4; ++j) {
                int col = tn * 128 + wn + j * 16 + c0;   // e
                int h = col >> 6, d = col & 63;
                int row0 = tm * 128 + wm + i * 16 + r0;  // s, 4 contiguous
                ushort4 o;
                o.x = f32_to_bf16(acc[i][j][0]);
                o.y = f32_to_bf16(acc[i][j][1]);
                o.z = f32_to_bf16(acc[i][j][2]);
                o.w = f32_to_bf16(acc[i][j][3]);
                *(ushort4*)&Vt[((size_t)h * HDIM + d) * S_LEN + row0] = o;
            }
        }
    }
}

// ---------------- flash attention: MFMA, one block per (q-tile=64, head) ----------------
__global__ __launch_bounds__(256) void flash_attn_kernel(
    const ushort* __restrict__ Qb,   // [H][S][64] bf16 roped
    const ushort* __restrict__ Kb,   // [H][S][64] bf16 roped
    const ushort* __restrict__ Vt,   // [H][64][S] bf16
    const int*   __restrict__ spike, // [S] 0/1
    float* __restrict__ out)         // [S][1536]
{
    const int qt = blockIdx.x;       // 0..31
    const int h  = blockIdx.y;       // 0..23
    const int qs = qt * 64;
    const int tid  = threadIdx.x;
    const int wave = tid >> 6;
    const int lane = tid & 63;
    const int quad = lane >> 4;
    const int l16  = lane & 15;

    __shared__ __align__(16) ushort Pst[4][16 * 72];   // per-wave P staging (stride 72)

    const ushort* Qp = Qb + ((size_t)h * S_LEN + qs + wave * 16 + l16) * HDIM;
    const short8 qf0 = *(const short8*)(Qp + quad * 8);
    const short8 qf1 = *(const short8*)(Qp + 32 + quad * 8);

    const int qrow0 = qs + wave * 16 + quad * 4;

    float m_i[4], l_i[4];
    floatx4 Oacc[4];
#pragma unroll
    for (int r = 0; r < 4; ++r) { m_i[r] = -INFINITY; l_i[r] = 0.f; }
#pragma unroll
    for (int j = 0; j < 4; ++j) Oacc[j] = (floatx4){0.f, 0.f, 0.f, 0.f};

    const int lo = (qs > WINDOW ? qs - WINDOW : 0) >> 6;

    for (int t = (lo > 0 ? -1 : 0); t <= qt; t = (t == -1 ? lo : t + 1)) {
        const int kt = (t == -1) ? 0 : t;
        const int kbase = kt * 64;

        // ---- QK^T ----
        floatx4 Sacc[4];
#pragma unroll
        for (int j = 0; j < 4; ++j) {
            const ushort* Kp = Kb + ((size_t)h * S_LEN + kbase + j * 16 + l16) * HDIM;
            short8 kf0 = *(const short8*)(Kp + quad * 8);
            short8 kf1 = *(const short8*)(Kp + 32 + quad * 8);
            floatx4 s = (floatx4){0.f, 0.f, 0.f, 0.f};
            s = __builtin_amdgcn_mfma_f32_16x16x32_bf16(qf0, kf0, s, 0, 0, 0);
            s = __builtin_amdgcn_mfma_f32_16x16x32_bf16(qf1, kf1, s, 0, 0, 0);
            Sacc[j] = s;
        }

        int spk[4];
#pragma unroll
        for (int j = 0; j < 4; ++j) spk[j] = spike[kbase + j * 16 + l16];

        // ---- mask + online softmax ----
        float p[4][4];   // [j][r]
#pragma unroll
        for (int r = 0; r < 4; ++r) {
            const int q = qrow0 + r;
            float mx = -INFINITY;
#pragma unroll
            for (int j = 0; j < 4; ++j) {
                const int k = kbase + j * 16 + l16;
                const bool valid = (k <= q) && (((q - k) <= WINDOW) || (k < NANCH)) && (spk[j] != 0);
                float s = valid ? Sacc[j][r] * 0.125f : -INFINITY;
                p[j][r] = s;
                mx = fmaxf(mx, s);
            }
            mx = fmaxf(mx, __shfl_xor(mx, 1));
            mx = fmaxf(mx, __shfl_xor(mx, 2));
            mx = fmaxf(mx, __shfl_xor(mx, 4));
            mx = fmaxf(mx, __shfl_xor(mx, 8));
            const float mnew = fmaxf(m_i[r], mx);
            const float alpha = (m_i[r] == -INFINITY) ? 0.f : __expf(m_i[r] - mnew);
            float rs = 0.f;
#pragma unroll
            for (int j = 0; j < 4; ++j) {
                float w = (p[j][r] == -INFINITY) ? 0.f : __expf(p[j][r] - mnew);
                p[j][r] = w;
                rs += w;
            }
            rs += __shfl_xor(rs, 1);
            rs += __shfl_xor(rs, 2);
            rs += __shfl_xor(rs, 4);
            rs += __shfl_xor(rs, 8);
            l_i[r] = l_i[r] * alpha + rs;
            m_i[r] = mnew;
#pragma unroll
            for (int j = 0; j < 4; ++j) Oacc[j][r] *= alpha;
        }

        // ---- P -> LDS (bf16, C-layout -> A-layout transpose) ----
        ushort* myP = Pst[wave];
#pragma unroll
        for (int r = 0; r < 4; ++r)
#pragma unroll
            for (int j = 0; j < 4; ++j)
                myP[(quad * 4 + r) * 72 + j * 16 + l16] = f32_to_bf16(p[j][r]);
        __syncthreads();

        // ---- P @ V ----
#pragma unroll
        for (int kk = 0; kk < 2; ++kk) {
            const short8 pf = *(const short8*)(myP + l16 * 72 + kk * 32 + quad * 8);
#pragma unroll
            for (int j = 0; j < 4; ++j) {
                const ushort* Vp = Vt + ((size_t)h * HDIM + j * 16 + l16) * S_LEN
                                 + kbase + kk * 32 + quad * 8;
                short8 vf = *(const short8*)Vp;
                Oacc[j] = __builtin_amdgcn_mfma_f32_16x16x32_bf16(pf, vf, Oacc[j], 0, 0, 0);
            }
        }
        __syncthreads();
    }

    // ---- epilogue: normalize, apply spike[q], write ----
#pragma unroll
    for (int r = 0; r < 4; ++r) {
        const int q = qrow0 + r;
        const float inv = (l_i[r] > 0.f && spike[q] != 0) ? (1.0f / l_i[r]) : 0.f;
#pragma unroll
        for (int j = 0; j < 4; ++j)
            out[(size_t)q * D_MODEL + h * HDIM + j * 16 + l16] = Oacc[j][r] * inv;
    }
}

extern "C" void kernel_launch(void* const* d_in, const int* in_sizes, int n_in,
                              void* d_out, int out_size, void* d_ws, size_t ws_size,
                              hipStream_t stream) {
    const float* x     = (const float*)d_in[0];
    const uint8_t* spike_raw = (const uint8_t*)d_in[1];
    const float* Wq    = (const float*)d_in[2];
    const float* Wk    = (const float*)d_in[3];
    const float* Wv    = (const float*)d_in[4];
    float* out = (float*)d_out;

    const size_t xb_elems = (size_t)S_LEN * D_MODEL;          // 3,145,728
    const size_t w_elems  = (size_t)D_MODEL * D_MODEL;        // 2,359,296
    const size_t hs_elems = (size_t)NH * S_LEN * HDIM;        // 3,145,728

    char* ws = (char*)d_ws;
    size_t off = 0;
    ushort* xb = (ushort*)(ws + off); off += xb_elems * 2;        // 6.29 MB
    ushort* wb = (ushort*)(ws + off); off += 3 * w_elems * 2;     // 14.16 MB
    ushort* Qb = (ushort*)(ws + off); off += hs_elems * 2;        // 6.29 MB
    ushort* Kb = (ushort*)(ws + off); off += hs_elems * 2;        // 6.29 MB
    ushort* Vt = (ushort*)(ws + off); off += hs_elems * 2;        // 6.29 MB
    float*  cst = (float*)(ws + off); off += (size_t)S_LEN * 64 * 4;  // 512 KB
    int* spike_i = (int*)(ws + off); off += S_LEN * 4;
    if (ws_size < off) return;

    // 0) RoPE table + spike normalize
    prep_kernel<<<257, 256, 0, stream>>>(spike_raw, spike_i, cst);

    // 1) fp32 -> bf16 (x, Wq, Wk, Wv)
    {
        int xq4 = (int)(xb_elems / 4);   // 786,432
        int wq4 = (int)(w_elems / 4);    // 589,824
        f2bf4_kernel<<<dim3((xq4 + 255) / 256, 4), 256, 0, stream>>>(
            x, Wq, Wk, Wv, xb, wb, xq4, wq4);
    }

    // 2) QKV projections (bf16 MFMA, global_load_lds staging) + fused RoPE
    gemm_qkv_kernel<<<dim3(S_LEN / 128, D_MODEL / 128, 3), 256, 0, stream>>>(
        xb, wb, cst, Qb, Kb, Vt);

    // 3) flash attention (MFMA)
    flash_attn_kernel<<<dim3(S_LEN / 64, NH), 256, 0, stream>>>(Qb, Kb, Vt, spike_i, out);
}